// Round 9
// baseline (90.260 us; speedup 1.0000x reference)
//
#include <hip/hip_runtime.h>
#include <math.h>

#define B_    32
#define NB_   1024
#define H_    768
#define K_    384
#define C_    64
#define NSTEP_ 24                // 24 K-steps of 32

typedef __attribute__((ext_vector_type(8))) short bf16x8;
typedef __attribute__((ext_vector_type(4))) float f32x4;

__device__ __forceinline__ short f2bf(float f) {   // RNE fp32 -> bf16 bits
    unsigned u = __float_as_uint(f);
    unsigned r = (u + 0x7fffu + ((u >> 16) & 1u)) >> 16;
    return (short)r;
}
__device__ __forceinline__ bf16x8 cvt8(const float4& a, const float4& b) {
    bf16x8 v = { f2bf(a.x), f2bf(a.y), f2bf(a.z), f2bf(a.w),
                 f2bf(b.x), f2bf(b.y), f2bf(b.z), f2bf(b.w) };
    return v;
}
__device__ __forceinline__ float ftanh(float x) {  // tanh = 1 - 2/(e^2x+1)
    float e = __expf(2.f * x);
    return 1.f - 2.f * __builtin_amdgcn_rcpf(e + 1.f);
}

// ---------------------------------------------------------------------------
// W1 (768x384 fp32) -> bf16 swizzled to exact MFMA B-fragment order.
// frag (s,t): lane l, elem i = W1[s*32+(l>>4)*8+i][t*16+(l&15)]
// ---------------------------------------------------------------------------
__global__ __launch_bounds__(256) void prep_w1(const float* __restrict__ W1,
                                               short* __restrict__ swz)
{
    int idx = blockIdx.x * 256 + threadIdx.x;
    int k = idx / K_, n = idx % K_;
    float v = W1[idx];
    int s = k >> 5, g = (k >> 3) & 3, i = k & 7;
    int t = n >> 4, nn = n & 15;
    swz[((s * 24 + t) * 512) + (g * 16 + nn) * 8 + i] = f2bf(v);
}

// ---------------------------------------------------------------------------
// Per-batch compaction of active rows. 1 block per b, 1024 threads.
// ---------------------------------------------------------------------------
__global__ __launch_bounds__(1024) void compact_kernel(
    const int* __restrict__ active, int* __restrict__ list, int* __restrict__ cnt)
{
    __shared__ int wsum[16];
    __shared__ int wbase[17];
    const int b = blockIdx.x, tid = threadIdx.x, lane = tid & 63, wid = tid >> 6;
    const int flag = active[b * NB_ + tid] != 0;
    const unsigned long long m = __ballot(flag);
    if (lane == 0) wsum[wid] = __popcll(m);
    __syncthreads();
    if (tid == 0) {
        int r = 0;
        for (int i = 0; i < 16; ++i) { wbase[i] = r; r += wsum[i]; }
        wbase[16] = r;
        cnt[b] = r;
    }
    __syncthreads();
    const int total = wbase[16];
    if (flag) {
        const int pos = wbase[wid] + __popcll(m & ((1ull << lane) - 1ull));
        list[b * NB_ + pos] = tid;
    }
    if (tid >= total) list[b * NB_ + tid] = 0;
}

// ---------------------------------------------------------------------------
// Gate MLP via MFMA — fully decoupled waves, NO LDS / NO barriers in main loop.
// Block: 256 thr = 4 waves; all waves share 32 list-rows; wave w owns cols
// [w*96, w*96+96) (6 B-frags). Per k-step per wave:
//   convert A slot (loaded 3 steps ago) -> 2 frags,
//   prefetch A[s+3] (4x dwordx4, HBM, ring-3),
//   prefetch B[s+2] (6x 1KB, L2, ring-3),
//   12 MFMA.
// A frags load straight from global in MFMA layout: lane l reads rows
// (l&15)[+16], bytes [kg*32 .. +32) of each 128B k-step segment (16 aligned
// 128-B lines per instr pair -> coalesced).
// ---------------------------------------------------------------------------
__global__ __launch_bounds__(256, 2) void gate_kernel(
    const float* __restrict__ tokens, const short* __restrict__ swz,
    const float* __restrict__ b1, const float* __restrict__ W2,
    const float* __restrict__ b2, const int* __restrict__ list,
    const int* __restrict__ cnt, float* __restrict__ gate)
{
    __shared__ float red[4][32];

    const int b = blockIdx.x >> 5;
    const int chunk = blockIdx.x & 31;
    if (chunk * 32 >= cnt[b]) return;             // uniform early-exit

    const int tid  = threadIdx.x;
    const int lane = tid & 63;
    const int w    = tid >> 6;                    // wave 0..3
    const int lrow = lane & 15;                   // row-within-frag
    const int kg   = lane >> 4;                   // 8-k subchunk 0..3

    const int n0 = list[b * NB_ + chunk * 32 + lrow];
    const int n1 = list[b * NB_ + chunk * 32 + 16 + lrow];
    const float* ap0 = tokens + ((size_t)b * NB_ + n0) * H_ + kg * 8;
    const float* ap1 = tokens + ((size_t)b * NB_ + n1) * H_ + kg * 8;
    const short* bbase = swz + (w * 6) * 512 + lane * 8;

    f32x4 acc[6][2];
#pragma unroll
    for (int j = 0; j < 6; ++j)
#pragma unroll
        for (int f = 0; f < 2; ++f) acc[j][f] = (f32x4){0.f, 0.f, 0.f, 0.f};

    float4 pa[3][4];       // A ring: [slot][frag0 lo/hi, frag1 lo/hi]
    bf16x8 bs[3][6];       // B ring

    // ---- prologue: A steps 0..2 -> slots 0..2; B steps 0,1 -> slots 0,1
#pragma unroll
    for (int s = 0; s < 3; ++s) {
        pa[s][0] = *(const float4*)(ap0 + s * 32);
        pa[s][1] = *(const float4*)(ap0 + s * 32 + 4);
        pa[s][2] = *(const float4*)(ap1 + s * 32);
        pa[s][3] = *(const float4*)(ap1 + s * 32 + 4);
    }
#pragma unroll
    for (int s = 0; s < 2; ++s)
#pragma unroll
        for (int j = 0; j < 6; ++j)
            bs[s][j] = *(const bf16x8*)(bbase + s * 12288 + j * 512);

    // ---- main loop: fully unrolled, zero barriers, zero LDS
#pragma unroll
    for (int s = 0; s < NSTEP_; ++s) {
        // convert this step's A (arrived >= 3 steps of issue ago)
        bf16x8 a0 = cvt8(pa[s % 3][0], pa[s % 3][1]);
        bf16x8 a1 = cvt8(pa[s % 3][2], pa[s % 3][3]);
        // refill the just-freed A slot with step s+3
        if (s + 3 < NSTEP_) {
            pa[s % 3][0] = *(const float4*)(ap0 + (s + 3) * 32);
            pa[s % 3][1] = *(const float4*)(ap0 + (s + 3) * 32 + 4);
            pa[s % 3][2] = *(const float4*)(ap1 + (s + 3) * 32);
            pa[s % 3][3] = *(const float4*)(ap1 + (s + 3) * 32 + 4);
        }
        // prefetch B step s+2 into the free slot
        if (s + 2 < NSTEP_) {
            const short* bp = bbase + (size_t)(s + 2) * 12288;
#pragma unroll
            for (int j = 0; j < 6; ++j)
                bs[(s + 2) % 3][j] = *(const bf16x8*)(bp + j * 512);
        }
#pragma unroll
        for (int j = 0; j < 6; ++j) {
            acc[j][0] = __builtin_amdgcn_mfma_f32_16x16x32_bf16(
                            a0, bs[s % 3][j], acc[j][0], 0, 0, 0);
            acc[j][1] = __builtin_amdgcn_mfma_f32_16x16x32_bf16(
                            a1, bs[s % 3][j], acc[j][1], 0, 0, 0);
        }
    }

    // ---- epilogue: gate[row] = b2 + sum_n tanh(h + b1[n]) * W2[n]
    float ps[2][4];
#pragma unroll
    for (int f = 0; f < 2; ++f)
#pragma unroll
        for (int rr = 0; rr < 4; ++rr) ps[f][rr] = 0.f;

#pragma unroll
    for (int j = 0; j < 6; ++j) {
        const int n = (w * 6 + j) * 16 + lrow;
        const float bb = b1[n];
        const float ww = W2[n];
#pragma unroll
        for (int f = 0; f < 2; ++f)
#pragma unroll
            for (int rr = 0; rr < 4; ++rr)
                ps[f][rr] += ftanh(acc[j][f][rr] + bb) * ww;
    }
    // sum over the 16 cols (lane bits 0..3)
#pragma unroll
    for (int m = 1; m < 16; m <<= 1)
#pragma unroll
        for (int f = 0; f < 2; ++f)
#pragma unroll
            for (int rr = 0; rr < 4; ++rr)
                ps[f][rr] += __shfl_xor(ps[f][rr], m, 64);

    if (lrow == 0) {
#pragma unroll
        for (int f = 0; f < 2; ++f)
#pragma unroll
            for (int rr = 0; rr < 4; ++rr)
                red[w][f * 16 + kg * 4 + rr] = ps[f][rr];
    }
    __syncthreads();
    if (tid < 32) {
        float sg = b2[0];
#pragma unroll
        for (int q = 0; q < 4; ++q) sg += red[q][tid];
        gate[b * NB_ + list[b * NB_ + chunk * 32 + tid]] = sg;
    }
}

// ---------------------------------------------------------------------------
// Per-(b,c) masked softmax + weighted token sum; compacted phase C, float4.
// ---------------------------------------------------------------------------
__global__ __launch_bounds__(256) void agg_kernel(
    const float* __restrict__ tokens, const int* __restrict__ active,
    const int* __restrict__ cmap, const float* __restrict__ gate,
    float* __restrict__ out_tok, float* __restrict__ out_act)
{
    __shared__ float wls[NB_];
    __shared__ float red[256];
    __shared__ int   idxs[NB_];
    __shared__ float wts[NB_];
    __shared__ int   gbase[17];

    const int b = blockIdx.x >> 6, c = blockIdx.x & 63;
    const int tid = threadIdx.x, lane = tid & 63, wid = tid >> 6;

    float lmax = -INFINITY;
    for (int n = tid; n < NB_; n += 256) {
        const bool msk = (active[b * NB_ + n] != 0) && (cmap[n] == c);
        const float g  = msk ? gate[b * NB_ + n] : -INFINITY;
        wls[n] = g;
        lmax = fmaxf(lmax, g);
    }
    red[tid] = lmax; __syncthreads();
    for (int s = 128; s > 0; s >>= 1) {
        if (tid < s) red[tid] = fmaxf(red[tid], red[tid + s]);
        __syncthreads();
    }
    const float m = red[0]; __syncthreads();
    const float msafe = (m > -INFINITY) ? m : 0.f;

    float lsum = 0.f;
    for (int n = tid; n < NB_; n += 256) {
        const float g = wls[n];
        const float e = (g > -INFINITY) ? __expf(g - msafe) : 0.f;
        wls[n] = e; lsum += e;
    }
    red[tid] = lsum; __syncthreads();
    for (int s = 128; s > 0; s >>= 1) {
        if (tid < s) red[tid] += red[tid + s];
        __syncthreads();
    }
    const float ssum = red[0];
    const float inv  = (ssum > 0.f) ? 1.f / ssum : 0.f;
    __syncthreads();

#pragma unroll
    for (int it = 0; it < 4; ++it) {
        const int n = it * 256 + wid * 64 + lane;
        const unsigned long long mask = __ballot(wls[n] > 0.f);
        if (lane == 0) gbase[1 + it * 4 + wid] = __popcll(mask);
    }
    __syncthreads();
    if (tid == 0) {
        gbase[0] = 0;
        for (int i = 1; i <= 16; ++i) gbase[i] += gbase[i - 1];
    }
    __syncthreads();
#pragma unroll
    for (int it = 0; it < 4; ++it) {
        const int n = it * 256 + wid * 64 + lane;
        const float e = wls[n];
        const unsigned long long mask = __ballot(e > 0.f);
        if (e > 0.f) {
            const int pos = gbase[it * 4 + wid] +
                            __popcll(mask & ((1ull << lane) - 1ull));
            idxs[pos] = n;
            wts[pos]  = e * inv;
        }
    }
    __syncthreads();
    const int cnt = gbase[16];

    // phase C: weighted accumulation, float4 (192 lanes x 16 B per row)
    if (tid < 192) {
        const int d = tid * 4;
        const float* tb = tokens + (size_t)b * NB_ * H_ + d;
        float4 a = {0.f, 0.f, 0.f, 0.f};
        for (int i = 0; i < cnt; ++i) {
            const float wv = wts[i];
            const float4 v = *(const float4*)(tb + (size_t)idxs[i] * H_);
            a.x += wv * v.x; a.y += wv * v.y;
            a.z += wv * v.z; a.w += wv * v.w;
        }
        *(float4*)(out_tok + ((size_t)(b * C_ + c)) * H_ + d) = a;
    }
    if (tid == 0) out_act[b * C_ + c] = (m > -INFINITY) ? 1.f : 0.f;
}

// ---------------------------------------------------------------------------
extern "C" void kernel_launch(void* const* d_in, const int* in_sizes, int n_in,
                              void* d_out, int out_size, void* d_ws, size_t ws_size,
                              hipStream_t stream)
{
    const float* tokens = (const float*)d_in[0];
    const int*   active = (const int*)  d_in[1];
    const int*   cmap   = (const int*)  d_in[2];
    const float* W1     = (const float*)d_in[3];
    const float* b1     = (const float*)d_in[4];
    const float* W2     = (const float*)d_in[5];
    const float* b2     = (const float*)d_in[6];

    float* out      = (float*)d_out;
    float* out_act  = out + (size_t)B_ * C_ * H_;

    short* swz     = (short*)d_ws;                          // 589824 B
    float* gate_ws = (float*)((char*)d_ws + 589824);        // 131072 B
    int*   list    = (int*)  ((char*)d_ws + 720896);        // 131072 B
    int*   cntb    = (int*)  ((char*)d_ws + 851968);        // 128 B

    compact_kernel<<<B_, 1024, 0, stream>>>(active, list, cntb);
    prep_w1<<<(H_ * K_) / 256, 256, 0, stream>>>(W1, swz);
    gate_kernel<<<B_ * 32, 256, 0, stream>>>(tokens, swz, b1, W2, b2, list, cntb, gate_ws);
    agg_kernel<<<B_ * C_, 256, 0, stream>>>(tokens, active, cmap, gate_ws, out, out_act);
}

// Round 10
// 56.207 us; speedup vs baseline: 1.6059x; 1.6059x over previous
//
#include <hip/hip_runtime.h>
#include <math.h>

#define B_    32
#define NB_   1024
#define H_    768
#define K_    384
#define C_    64
#define NSTEP_ 24                // 24 K-steps of 32

typedef __attribute__((ext_vector_type(8))) short bf16x8;
typedef __attribute__((ext_vector_type(4))) float f32x4;

__device__ __forceinline__ short f2bf(float f) {   // RNE fp32 -> bf16 bits
    unsigned u = __float_as_uint(f);
    unsigned r = (u + 0x7fffu + ((u >> 16) & 1u)) >> 16;
    return (short)r;
}
__device__ __forceinline__ float ftanh(float x) {  // tanh = 1 - 2/(e^2x+1)
    float e = __expf(2.f * x);
    return 1.f - 2.f * __builtin_amdgcn_rcpf(e + 1.f);
}

// ---------------------------------------------------------------------------
// W1 (768x384 fp32) -> bf16 swizzled to exact MFMA B-fragment order.
// frag (s,t): lane l, elem i = W1[s*32+(l>>4)*8+i][t*16+(l&15)]
// ---------------------------------------------------------------------------
__global__ __launch_bounds__(256) void prep_w1(const float* __restrict__ W1,
                                               short* __restrict__ swz)
{
    int idx = blockIdx.x * 256 + threadIdx.x;
    int k = idx / K_, n = idx % K_;
    float v = W1[idx];
    int s = k >> 5, g = (k >> 3) & 3, i = k & 7;
    int t = n >> 4, nn = n & 15;
    swz[((s * 24 + t) * 512) + (g * 16 + nn) * 8 + i] = f2bf(v);
}

// ---------------------------------------------------------------------------
// Per-batch compaction of active rows. 1 block per b, 1024 threads.
// ---------------------------------------------------------------------------
__global__ __launch_bounds__(1024) void compact_kernel(
    const int* __restrict__ active, int* __restrict__ list, int* __restrict__ cnt)
{
    __shared__ int wsum[16];
    __shared__ int wbase[17];
    const int b = blockIdx.x, tid = threadIdx.x, lane = tid & 63, wid = tid >> 6;
    const int flag = active[b * NB_ + tid] != 0;
    const unsigned long long m = __ballot(flag);
    if (lane == 0) wsum[wid] = __popcll(m);
    __syncthreads();
    if (tid == 0) {
        int r = 0;
        for (int i = 0; i < 16; ++i) { wbase[i] = r; r += wsum[i]; }
        wbase[16] = r;
        cnt[b] = r;
    }
    __syncthreads();
    const int total = wbase[16];
    if (flag) {
        const int pos = wbase[wid] + __popcll(m & ((1ull << lane) - 1ull));
        list[b * NB_ + pos] = tid;
    }
    if (tid >= total) list[b * NB_ + tid] = 0;
}

// ---------------------------------------------------------------------------
// Gate MLP via MFMA — 8-wave blocks for 2x wave-level parallelism.
// Block: 512 thr (8 waves) = 32 rows x 384 cols; wave w owns cols [w*48,+48)
// (3 B-frags, L2-resident, named distance-2 ring, no arrays).
// A staged to LDS ONCE (48 KiB, verified fragment layout + XOR swizzle),
// a single __syncthreads, then a barrier-free, asm-free main loop:
// per step/wave: 2 ds_read_b128 + 3 B loads + 6 MFMA.
// ---------------------------------------------------------------------------
__global__ __launch_bounds__(512, 4) void gate_kernel(
    const float* __restrict__ tokens, const short* __restrict__ swz,
    const float* __restrict__ b1, const float* __restrict__ W2,
    const float* __restrict__ b2, const int* __restrict__ list,
    const int* __restrict__ cnt, float* __restrict__ gate)
{
    __shared__ __align__(16) short As[NSTEP_ * 1024];  // 48 KiB (32x768 bf16)
    __shared__ float red[8][32];

    const int b = blockIdx.x >> 5;
    const int chunk = blockIdx.x & 31;
    if (chunk * 32 >= cnt[b]) return;             // uniform early-exit

    const int tid  = threadIdx.x;                 // 0..511
    const int lane = tid & 63;
    const int w    = tid >> 6;                    // wave 0..7
    const int lrow = lane & 15;
    const int kg   = lane >> 4;                   // 0..3

    // ---- Phase 1: stage the whole 32x768 A-tile (row r, 12 float4/thread)
    {
        const int r   = tid >> 4;                 // 0..31
        const int j4b = tid & 15;                 // float4 phase within row
        const int nrow = list[b * NB_ + chunk * 32 + r];
        const float* arow = tokens + ((size_t)b * NB_ + nrow) * H_;
        const int fw = r >> 4, roww = r & 15;

        float4 st[12];
#pragma unroll
        for (int q = 0; q < 12; ++q)
            st[q] = *(const float4*)(arow + (j4b + 16 * q) * 4);
#pragma unroll
        for (int q = 0; q < 12; ++q) {
            const int j4   = j4b + 16 * q;
            const int step = j4 >> 3;             // k-step 0..23
            const int c8   = j4 & 7;              // 4-float chunk within step
            const int g2w  = c8 >> 1, hw = c8 & 1;
            const int woff = ((fw * 4 + g2w) * 16 + (roww ^ (g2w << 1))) * 8 + hw * 4;
            short4 av = {f2bf(st[q].x), f2bf(st[q].y), f2bf(st[q].z), f2bf(st[q].w)};
            *(short4*)&As[step * 1024 + woff] = av;
        }
    }

    // ---- A fragment read geometry (lane -> 8 bf16), verified layout
    const int rowr  = lrow ^ (kg << 1);
    const int roff0 = ((0 + kg) * 16 + rowr) * 8;
    const int roff1 = ((4 + kg) * 16 + rowr) * 8;

    const short* bbase = swz + (w * 3) * 512 + lane * 8;

    f32x4 acc[3][2];
#pragma unroll
    for (int j = 0; j < 3; ++j)
#pragma unroll
        for (int f = 0; f < 2; ++f) acc[j][f] = (f32x4){0.f, 0.f, 0.f, 0.f};

    // B prologue: steps 0 (E) and 1 (O) — named, no arrays
    bf16x8 bE0 = *(const bf16x8*)(bbase + 0 * 12288 + 0 * 512);
    bf16x8 bE1 = *(const bf16x8*)(bbase + 0 * 12288 + 1 * 512);
    bf16x8 bE2 = *(const bf16x8*)(bbase + 0 * 12288 + 2 * 512);
    bf16x8 bO0 = *(const bf16x8*)(bbase + 1 * 12288 + 0 * 512);
    bf16x8 bO1 = *(const bf16x8*)(bbase + 1 * 12288 + 1 * 512);
    bf16x8 bO2 = *(const bf16x8*)(bbase + 1 * 12288 + 2 * 512);

    // ---- Phase 2: the single block-wide barrier
    __syncthreads();

    // ---- Phase 3: barrier-free main loop (12 x 2 steps)
    for (int s = 0; s < NSTEP_; s += 2) {
        // even step s: consume bE*, refill bE* with step s+2 after MFMA
        {
            bf16x8 a0 = *(const bf16x8*)&As[s * 1024 + roff0];
            bf16x8 a1 = *(const bf16x8*)&As[s * 1024 + roff1];
            acc[0][0] = __builtin_amdgcn_mfma_f32_16x16x32_bf16(a0, bE0, acc[0][0], 0, 0, 0);
            acc[0][1] = __builtin_amdgcn_mfma_f32_16x16x32_bf16(a1, bE0, acc[0][1], 0, 0, 0);
            acc[1][0] = __builtin_amdgcn_mfma_f32_16x16x32_bf16(a0, bE1, acc[1][0], 0, 0, 0);
            acc[1][1] = __builtin_amdgcn_mfma_f32_16x16x32_bf16(a1, bE1, acc[1][1], 0, 0, 0);
            acc[2][0] = __builtin_amdgcn_mfma_f32_16x16x32_bf16(a0, bE2, acc[2][0], 0, 0, 0);
            acc[2][1] = __builtin_amdgcn_mfma_f32_16x16x32_bf16(a1, bE2, acc[2][1], 0, 0, 0);
        }
        if (s + 2 < NSTEP_) {
            const short* bp = bbase + (s + 2) * 12288;
            bE0 = *(const bf16x8*)(bp + 0 * 512);
            bE1 = *(const bf16x8*)(bp + 1 * 512);
            bE2 = *(const bf16x8*)(bp + 2 * 512);
        }
        // odd step s+1: consume bO*, refill bO* with step s+3 after MFMA
        {
            bf16x8 a0 = *(const bf16x8*)&As[(s + 1) * 1024 + roff0];
            bf16x8 a1 = *(const bf16x8*)&As[(s + 1) * 1024 + roff1];
            acc[0][0] = __builtin_amdgcn_mfma_f32_16x16x32_bf16(a0, bO0, acc[0][0], 0, 0, 0);
            acc[0][1] = __builtin_amdgcn_mfma_f32_16x16x32_bf16(a1, bO0, acc[0][1], 0, 0, 0);
            acc[1][0] = __builtin_amdgcn_mfma_f32_16x16x32_bf16(a0, bO1, acc[1][0], 0, 0, 0);
            acc[1][1] = __builtin_amdgcn_mfma_f32_16x16x32_bf16(a1, bO1, acc[1][1], 0, 0, 0);
            acc[2][0] = __builtin_amdgcn_mfma_f32_16x16x32_bf16(a0, bO2, acc[2][0], 0, 0, 0);
            acc[2][1] = __builtin_amdgcn_mfma_f32_16x16x32_bf16(a1, bO2, acc[2][1], 0, 0, 0);
        }
        if (s + 3 < NSTEP_) {
            const short* bp = bbase + (s + 3) * 12288;
            bO0 = *(const bf16x8*)(bp + 0 * 512);
            bO1 = *(const bf16x8*)(bp + 1 * 512);
            bO2 = *(const bf16x8*)(bp + 2 * 512);
        }
    }

    // ---- epilogue: gate[row] = b2 + sum_n tanh(h + b1[n]) * W2[n]
    float ps[2][4];
#pragma unroll
    for (int f = 0; f < 2; ++f)
#pragma unroll
        for (int rr = 0; rr < 4; ++rr) ps[f][rr] = 0.f;

#pragma unroll
    for (int j = 0; j < 3; ++j) {
        const int n  = (w * 3 + j) * 16 + lrow;
        const float bb = b1[n];
        const float ww = W2[n];
#pragma unroll
        for (int f = 0; f < 2; ++f)
#pragma unroll
            for (int rr = 0; rr < 4; ++rr)
                ps[f][rr] += ftanh(acc[j][f][rr] + bb) * ww;
    }
    // sum across the 16 lanes sharing a row-group (lane bits 0..3)
#pragma unroll
    for (int m = 1; m < 16; m <<= 1)
#pragma unroll
        for (int f = 0; f < 2; ++f)
#pragma unroll
            for (int rr = 0; rr < 4; ++rr)
                ps[f][rr] += __shfl_xor(ps[f][rr], m, 64);

    if (lrow == 0) {
#pragma unroll
        for (int f = 0; f < 2; ++f)
#pragma unroll
            for (int rr = 0; rr < 4; ++rr)
                red[w][f * 16 + kg * 4 + rr] = ps[f][rr];
    }
    __syncthreads();
    if (tid < 32) {
        float sg = b2[0];
#pragma unroll
        for (int q = 0; q < 8; ++q) sg += red[q][tid];
        gate[b * NB_ + list[b * NB_ + chunk * 32 + tid]] = sg;
    }
}

// ---------------------------------------------------------------------------
// Per-(b,c) masked softmax + weighted token sum; compacted phase C, float4.
// ---------------------------------------------------------------------------
__global__ __launch_bounds__(256) void agg_kernel(
    const float* __restrict__ tokens, const int* __restrict__ active,
    const int* __restrict__ cmap, const float* __restrict__ gate,
    float* __restrict__ out_tok, float* __restrict__ out_act)
{
    __shared__ float wls[NB_];
    __shared__ float red[256];
    __shared__ int   idxs[NB_];
    __shared__ float wts[NB_];
    __shared__ int   gbase[17];

    const int b = blockIdx.x >> 6, c = blockIdx.x & 63;
    const int tid = threadIdx.x, lane = tid & 63, wid = tid >> 6;

    float lmax = -INFINITY;
    for (int n = tid; n < NB_; n += 256) {
        const bool msk = (active[b * NB_ + n] != 0) && (cmap[n] == c);
        const float g  = msk ? gate[b * NB_ + n] : -INFINITY;
        wls[n] = g;
        lmax = fmaxf(lmax, g);
    }
    red[tid] = lmax; __syncthreads();
    for (int s = 128; s > 0; s >>= 1) {
        if (tid < s) red[tid] = fmaxf(red[tid], red[tid + s]);
        __syncthreads();
    }
    const float m = red[0]; __syncthreads();
    const float msafe = (m > -INFINITY) ? m : 0.f;

    float lsum = 0.f;
    for (int n = tid; n < NB_; n += 256) {
        const float g = wls[n];
        const float e = (g > -INFINITY) ? __expf(g - msafe) : 0.f;
        wls[n] = e; lsum += e;
    }
    red[tid] = lsum; __syncthreads();
    for (int s = 128; s > 0; s >>= 1) {
        if (tid < s) red[tid] += red[tid + s];
        __syncthreads();
    }
    const float ssum = red[0];
    const float inv  = (ssum > 0.f) ? 1.f / ssum : 0.f;
    __syncthreads();

#pragma unroll
    for (int it = 0; it < 4; ++it) {
        const int n = it * 256 + wid * 64 + lane;
        const unsigned long long mask = __ballot(wls[n] > 0.f);
        if (lane == 0) gbase[1 + it * 4 + wid] = __popcll(mask);
    }
    __syncthreads();
    if (tid == 0) {
        gbase[0] = 0;
        for (int i = 1; i <= 16; ++i) gbase[i] += gbase[i - 1];
    }
    __syncthreads();
#pragma unroll
    for (int it = 0; it < 4; ++it) {
        const int n = it * 256 + wid * 64 + lane;
        const float e = wls[n];
        const unsigned long long mask = __ballot(e > 0.f);
        if (e > 0.f) {
            const int pos = gbase[it * 4 + wid] +
                            __popcll(mask & ((1ull << lane) - 1ull));
            idxs[pos] = n;
            wts[pos]  = e * inv;
        }
    }
    __syncthreads();
    const int cnt = gbase[16];

    // phase C: weighted accumulation, float4 (192 lanes x 16 B per row)
    if (tid < 192) {
        const int d = tid * 4;
        const float* tb = tokens + (size_t)b * NB_ * H_ + d;
        float4 a = {0.f, 0.f, 0.f, 0.f};
        for (int i = 0; i < cnt; ++i) {
            const float wv = wts[i];
            const float4 v = *(const float4*)(tb + (size_t)idxs[i] * H_);
            a.x += wv * v.x; a.y += wv * v.y;
            a.z += wv * v.z; a.w += wv * v.w;
        }
        *(float4*)(out_tok + ((size_t)(b * C_ + c)) * H_ + d) = a;
    }
    if (tid == 0) out_act[b * C_ + c] = (m > -INFINITY) ? 1.f : 0.f;
}

// ---------------------------------------------------------------------------
extern "C" void kernel_launch(void* const* d_in, const int* in_sizes, int n_in,
                              void* d_out, int out_size, void* d_ws, size_t ws_size,
                              hipStream_t stream)
{
    const float* tokens = (const float*)d_in[0];
    const int*   active = (const int*)  d_in[1];
    const int*   cmap   = (const int*)  d_in[2];
    const float* W1     = (const float*)d_in[3];
    const float* b1     = (const float*)d_in[4];
    const float* W2     = (const float*)d_in[5];
    const float* b2     = (const float*)d_in[6];

    float* out      = (float*)d_out;
    float* out_act  = out + (size_t)B_ * C_ * H_;

    short* swz     = (short*)d_ws;                          // 589824 B
    float* gate_ws = (float*)((char*)d_ws + 589824);        // 131072 B
    int*   list    = (int*)  ((char*)d_ws + 720896);        // 131072 B
    int*   cntb    = (int*)  ((char*)d_ws + 851968);        // 128 B

    compact_kernel<<<B_, 1024, 0, stream>>>(active, list, cntb);
    prep_w1<<<(H_ * K_) / 256, 256, 0, stream>>>(W1, swz);
    gate_kernel<<<B_ * 32, 512, 0, stream>>>(tokens, swz, b1, W2, b2, list, cntb, gate_ws);
    agg_kernel<<<B_ * C_, 256, 0, stream>>>(tokens, active, cmap, gate_ws, out, out_act);
}